// Round 1
// baseline (504.367 us; speedup 1.0000x reference)
//
#include <hip/hip_runtime.h>

#define BB 1024
#define VV 6890
#define NJ 24
#define NBETA 10
#define NP 207
#define NJOUT 61
#define OUTJ ((size_t)BB*VV*3)

// ws layout (floats): JT[72] @0, JS[720] @72, F[B*207] @800, A[B*288] @WS_A
#define WS_JT 0
#define WS_JS 72
#define WS_F  800
#define WS_A  (WS_F + BB*NP)

__constant__ int c_par[24] = {-1,0,0,0,1,2,3,4,5,6,7,8,9,9,9,12,13,14,16,17,18,19,20,21};

// ---------------- Kernel A: JT = Jreg@v_template, JS = Jreg@shapedirs ----------------
__global__ __launch_bounds__(256) void k_jointreg(
    const float* __restrict__ Jreg, const float* __restrict__ vt,
    const float* __restrict__ sd, float* __restrict__ ws)
{
    const int j = blockIdx.x / 3, k = blockIdx.x % 3;
    float acc[11];
#pragma unroll
    for (int i = 0; i < 11; i++) acc[i] = 0.f;
    for (int v = threadIdx.x; v < VV; v += 256) {
        const float jr = Jreg[j*VV + v];
        acc[0] += jr * vt[v*3 + k];
        const float* s = sd + (size_t)v*30 + k*10;
#pragma unroll
        for (int l = 0; l < 10; l++) acc[1+l] += jr * s[l];
    }
#pragma unroll
    for (int off = 1; off < 64; off <<= 1) {
#pragma unroll
        for (int i = 0; i < 11; i++) acc[i] += __shfl_xor(acc[i], off);
    }
    __shared__ float red[4][11];
    const int wv = threadIdx.x >> 6, ln = threadIdx.x & 63;
    if (ln == 0) {
#pragma unroll
        for (int i = 0; i < 11; i++) red[wv][i] = acc[i];
    }
    __syncthreads();
    if (threadIdx.x == 0) {
        ws[WS_JT + j*3 + k] = red[0][0]+red[1][0]+red[2][0]+red[3][0];
#pragma unroll
        for (int l = 0; l < 10; l++)
            ws[WS_JS + (j*3+k)*10 + l] = red[0][1+l]+red[1][1+l]+red[2][1+l]+red[3][1+l];
    }
}

// ------- Kernel B: per-batch rodrigues, pose_feature, kinematic chain, A, joints[0:24] -------
__global__ __launch_bounds__(64) void k_batch(
    const float* __restrict__ betas, const float* __restrict__ poses,
    float* __restrict__ ws, float* __restrict__ out)
{
    const int b = blockIdx.x, lane = threadIdx.x;
    __shared__ float R[24][9], Jr[24][3], RJ[24][3], G[24][12];
    if (lane < 24) {
        const int j = lane;
        const float x = poses[b*72 + j*3 + 0];
        const float y = poses[b*72 + j*3 + 1];
        const float z = poses[b*72 + j*3 + 2];
        const float xe = x + 1e-8f, ye = y + 1e-8f, ze = z + 1e-8f;
        const float ang = sqrtf(xe*xe + ye*ye + ze*ze);
        const float inv = 1.0f / ang;
        const float rx = x*inv, ry = y*inv, rz = z*inv;
        const float sn = sinf(ang), cs = cosf(ang);
        const float K[9] = {0.f,-rz,ry, rz,0.f,-rx, -ry,rx,0.f};
        float Rl[9];
#pragma unroll
        for (int r = 0; r < 3; r++) {
#pragma unroll
            for (int c = 0; c < 3; c++) {
                float kk = 0.f;
#pragma unroll
                for (int m = 0; m < 3; m++) kk += K[r*3+m]*K[m*3+c];
                const float id = (r == c) ? 1.f : 0.f;
                Rl[r*3+c] = id + sn*K[r*3+c] + (1.f-cs)*kk;
            }
        }
#pragma unroll
        for (int e = 0; e < 9; e++) R[j][e] = Rl[e];
        if (j >= 1) {
#pragma unroll
            for (int e = 0; e < 9; e++)
                ws[WS_F + (size_t)b*NP + (j-1)*9 + e] = Rl[e] - ((e % 4 == 0) ? 1.f : 0.f);
        }
#pragma unroll
        for (int k = 0; k < 3; k++) {
            float a = ws[WS_JT + j*3 + k];
#pragma unroll
            for (int l = 0; l < 10; l++) a += betas[b*10 + l] * ws[WS_JS + (j*3+k)*10 + l];
            Jr[j][k] = a;
        }
    }
    __syncthreads();
    if (lane < 24) {
        const int j = lane, p = c_par[j];
#pragma unroll
        for (int k = 0; k < 3; k++) RJ[j][k] = (j == 0) ? Jr[0][k] : (Jr[j][k] - Jr[p][k]);
    }
    __syncthreads();
    if (lane < 12) {
        const int r = lane >> 2, c = lane & 3;
        G[0][lane] = (c < 3) ? R[0][r*3+c] : RJ[0][r];
    }
    __syncthreads();
    for (int i = 1; i < 24; i++) {
        float val = 0.f;
        if (lane < 12) {
            const int r = lane >> 2, c = lane & 3, p = c_par[i];
            if (c < 3)
                val = G[p][r*4+0]*R[i][0+c] + G[p][r*4+1]*R[i][3+c] + G[p][r*4+2]*R[i][6+c];
            else
                val = G[p][r*4+0]*RJ[i][0] + G[p][r*4+1]*RJ[i][1] + G[p][r*4+2]*RJ[i][2] + G[p][r*4+3];
        }
        __syncthreads();
        if (lane < 12) G[i][lane] = val;
        __syncthreads();
    }
    if (lane < 24) {
#pragma unroll
        for (int k = 0; k < 3; k++)
            out[OUTJ + ((size_t)b*NJOUT + lane)*3 + k] = G[lane][k*4+3];
    }
    for (int e = lane; e < 288; e += 64) {
        const int j = e / 12, rc = e % 12, r = rc >> 2, c = rc & 3;
        float val = G[j][rc];
        if (c == 3)
            val -= G[j][r*4+0]*Jr[j][0] + G[j][r*4+1]*Jr[j][1] + G[j][r*4+2]*Jr[j][2];
        ws[WS_A + (size_t)b*288 + e] = val;
    }
}

// ------- Kernel C: fused shape-blend + pose GEMM + LBS; tile 128b x 32v, thread 8b x 2v -------
__global__ __launch_bounds__(256) void k_vertex(
    const float* __restrict__ betas, const float* __restrict__ vt,
    const float* __restrict__ sd, const float* __restrict__ pd,
    const float* __restrict__ lbsw, const float* __restrict__ ws,
    float* __restrict__ out)
{
    const int tid = threadIdx.x;
    const int vi = tid & 15;
    const int bg = tid >> 4;
    const int v0 = blockIdx.x * 32;
    const int b0 = blockIdx.y * 128;

    __shared__ float sm[8320] __attribute__((aligned(16)));
    float* Fs = sm;            // [32][132] (transposed pose features, padded stride)
    float* Ds = sm + 4224;     // [32][32][4] (posedirs, k padded to 4)

    float po[8][2][3];
#pragma unroll
    for (int a = 0; a < 8; a++)
#pragma unroll
        for (int b = 0; b < 2; b++)
#pragma unroll
            for (int c = 0; c < 3; c++) po[a][b][c] = 0.f;

    const float* Fg = ws + WS_F;
    for (int kc = 0; kc < 7; ++kc) {
        __syncthreads();
#pragma unroll
        for (int i = 0; i < 16; i++) {          // stage F (transposed): 32k x 128b
            const int idx = tid + i*256;
            const int brow = idx >> 5, kk = idx & 31;
            const int kg = kc*32 + kk;
            Fs[kk*132 + brow] = (kg < NP) ? Fg[(size_t)(b0+brow)*NP + kg] : 0.f;
        }
#pragma unroll
        for (int i = 0; i < 12; i++) {          // stage D: 32k x 96 cols -> [32][32][4]
            const int idx = tid + i*256;
            const int r = idx / 96, c = idx % 96;
            const int kg = kc*32 + r, col = v0*3 + c;
            float val = 0.f;
            if (kg < NP && col < VV*3) val = pd[(size_t)kg*(VV*3) + col];
            Ds[r*128 + (c/3)*4 + (c%3)] = val;
        }
        __syncthreads();
#pragma unroll 4
        for (int p = 0; p < 32; p++) {
            const float4 fA = *reinterpret_cast<const float4*>(&Fs[p*132 + bg*8]);
            const float4 fB = *reinterpret_cast<const float4*>(&Fs[p*132 + bg*8 + 4]);
            const float4 dA = *reinterpret_cast<const float4*>(&Ds[p*128 + vi*4]);
            const float4 dB = *reinterpret_cast<const float4*>(&Ds[p*128 + vi*4 + 64]);
            const float f[8] = {fA.x,fA.y,fA.z,fA.w,fB.x,fB.y,fB.z,fB.w};
#pragma unroll
            for (int ib = 0; ib < 8; ib++) {
                po[ib][0][0] += f[ib]*dA.x;
                po[ib][0][1] += f[ib]*dA.y;
                po[ib][0][2] += f[ib]*dA.z;
                po[ib][1][0] += f[ib]*dB.x;
                po[ib][1][1] += f[ib]*dB.y;
                po[ib][1][2] += f[ib]*dB.z;
            }
        }
    }
    __syncthreads();

    float* As = sm;            // [128][12] bg-swizzled (1600 floats)
    float* Bs = sm + 1600;     // [128][10]
    float* Ws = sm + 2880;     // [32][25]
    for (int idx = tid; idx < 1280; idx += 256) Bs[idx] = betas[b0*10 + idx];
    for (int idx = tid; idx < 768; idx += 256) {
        const int r = idx / 24, c = idx % 24;
        const int v = v0 + r;
        Ws[r*25 + c] = (v < VV) ? lbsw[(size_t)v*24 + c] : 0.f;
    }
    __syncthreads();

    const int vA = v0 + vi, vB = v0 + vi + 16;
    const int vAc = (vA < VV) ? vA : VV-1;
    const int vBc = (vB < VV) ? vB : VV-1;
#pragma unroll
    for (int k = 0; k < 3; k++) {               // + v_template
        const float tA = vt[vAc*3 + k], tB = vt[vBc*3 + k];
#pragma unroll
        for (int ib = 0; ib < 8; ib++) { po[ib][0][k] += tA; po[ib][1][k] += tB; }
    }
    const float* sdA = sd + (size_t)vAc*30;     // + betas @ shapedirs
    const float* sdB = sd + (size_t)vBc*30;
#pragma unroll
    for (int l = 0; l < 10; l++) {
        const float sA0 = sdA[l], sA1 = sdA[10+l], sA2 = sdA[20+l];
        const float sB0 = sdB[l], sB1 = sdB[10+l], sB2 = sdB[20+l];
#pragma unroll
        for (int ib = 0; ib < 8; ib++) {
            const float be = Bs[(bg*8+ib)*10 + l];
            po[ib][0][0] += be*sA0; po[ib][0][1] += be*sA1; po[ib][0][2] += be*sA2;
            po[ib][1][0] += be*sB0; po[ib][1][1] += be*sB1; po[ib][1][2] += be*sB2;
        }
    }

    float vo[8][2][3];
#pragma unroll
    for (int a = 0; a < 8; a++)
#pragma unroll
        for (int b = 0; b < 2; b++)
#pragma unroll
            for (int c = 0; c < 3; c++) vo[a][b][c] = 0.f;

    const float* Ag = ws + WS_A;
    for (int j = 0; j < 24; j++) {
        __syncthreads();
        for (int idx = tid; idx < 1536; idx += 256) {
            const int bb = idx / 12, e = idx % 12;
            As[bb*12 + (bb>>3)*4 + e] = Ag[(size_t)(b0+bb)*288 + j*12 + e];
        }
        __syncthreads();
        const float wvA = Ws[vi*25 + j], wvB = Ws[(vi+16)*25 + j];
#pragma unroll
        for (int ib = 0; ib < 8; ib++) {
            const int bb = bg*8 + ib;
            const float* a = &As[bb*12 + bg*4];
            const float4 a0 = *reinterpret_cast<const float4*>(a);
            const float4 a1 = *reinterpret_cast<const float4*>(a + 4);
            const float4 a2 = *reinterpret_cast<const float4*>(a + 8);
#pragma unroll
            for (int iv = 0; iv < 2; iv++) {
                const float ux = po[ib][iv][0], uy = po[ib][iv][1], uz = po[ib][iv][2];
                const float t0 = a0.x*ux + a0.y*uy + a0.z*uz + a0.w;
                const float t1 = a1.x*ux + a1.y*uy + a1.z*uz + a1.w;
                const float t2 = a2.x*ux + a2.y*uy + a2.z*uz + a2.w;
                const float w = iv ? wvB : wvA;
                vo[ib][iv][0] += w*t0;
                vo[ib][iv][1] += w*t1;
                vo[ib][iv][2] += w*t2;
            }
        }
    }
#pragma unroll
    for (int ib = 0; ib < 8; ib++) {
        const int b = b0 + bg*8 + ib;
#pragma unroll
        for (int iv = 0; iv < 2; iv++) {
            const int v = v0 + vi + iv*16;
            if (v < VV) {
                const size_t base = ((size_t)b*VV + v)*3;
                out[base+0] = vo[ib][iv][0];
                out[base+1] = vo[ib][iv][1];
                out[base+2] = vo[ib][iv][2];
            }
        }
    }
}

// ------- Kernel D: extra9 + h36m17 regressors + 11 gathered joints -------
__global__ __launch_bounds__(256) void k_joints(
    const float* __restrict__ Je9, const float* __restrict__ Jh,
    const int* __restrict__ eidx, float* __restrict__ out)
{
    const int b = blockIdx.x;
    const int wv = threadIdx.x >> 6, ln = threadIdx.x & 63;
    const int j0 = (wv == 0) ? 0 : (wv == 1) ? 7 : (wv == 2) ? 14 : 20;
    const int jn = (wv < 2) ? 7 : 6;
    float acc[7][3];
#pragma unroll
    for (int t = 0; t < 7; t++)
#pragma unroll
        for (int k = 0; k < 3; k++) acc[t][k] = 0.f;
    const float* vb = out + (size_t)b*VV*3;
    for (int v = ln; v < VV; v += 64) {
        const float x = vb[v*3+0], y = vb[v*3+1], z = vb[v*3+2];
#pragma unroll
        for (int t = 0; t < 7; t++) {
            if (t < jn) {
                const int jj = j0 + t;
                const float jr = (jj < 9) ? Je9[(size_t)jj*VV + v] : Jh[(size_t)(jj-9)*VV + v];
                acc[t][0] += jr*x; acc[t][1] += jr*y; acc[t][2] += jr*z;
            }
        }
    }
#pragma unroll
    for (int off = 1; off < 64; off <<= 1)
#pragma unroll
        for (int t = 0; t < 7; t++)
#pragma unroll
            for (int k = 0; k < 3; k++) acc[t][k] += __shfl_xor(acc[t][k], off);
    if (ln == 0) {
#pragma unroll
        for (int t = 0; t < 7; t++) {
            if (t < jn) {
#pragma unroll
                for (int k = 0; k < 3; k++)
                    out[OUTJ + ((size_t)b*NJOUT + 35 + j0 + t)*3 + k] = acc[t][k];
            }
        }
    }
    if (wv == 0 && ln < 33) {
        const int j = ln / 3, k = ln % 3;
        out[OUTJ + ((size_t)b*NJOUT + 24 + j)*3 + k] = vb[(size_t)eidx[j]*3 + k];
    }
}

extern "C" void kernel_launch(void* const* d_in, const int* in_sizes, int n_in,
                              void* d_out, int out_size, void* d_ws, size_t ws_size,
                              hipStream_t stream) {
    const float* betas = (const float*)d_in[0];
    const float* poses = (const float*)d_in[1];
    const int*   eidx  = (const int*)  d_in[2];
    const float* vt    = (const float*)d_in[3];
    const float* sd    = (const float*)d_in[4];
    const float* pd    = (const float*)d_in[5];
    const float* Jreg  = (const float*)d_in[6];
    const float* lbsw  = (const float*)d_in[7];
    const float* Je9   = (const float*)d_in[8];
    const float* Jh    = (const float*)d_in[9];
    float* out = (float*)d_out;
    float* ws  = (float*)d_ws;

    k_jointreg<<<dim3(72), dim3(256), 0, stream>>>(Jreg, vt, sd, ws);
    k_batch<<<dim3(1024), dim3(64), 0, stream>>>(betas, poses, ws, out);
    k_vertex<<<dim3(216, 8), dim3(256), 0, stream>>>(betas, vt, sd, pd, lbsw, ws, out);
    k_joints<<<dim3(1024), dim3(256), 0, stream>>>(Je9, Jh, eidx, out);
}